// Round 10
// baseline (77.841 us; speedup 1.0000x reference)
//
#include <hip/hip_runtime.h>

#define NB    8
#define NIN   512
#define TOUT  4096
#define ND    384
#define J4    (ND / 4)     // 96 float4 per row
#define TROWS 32           // output rows per block
#define BLK   512          // threads per block (8 waves)

typedef float f32x4 __attribute__((ext_vector_type(4)));

// Fused length-regulator, R10: one 512-thread block per 32 output rows.
// 1024 blocks = 4/CU = 32 waves/CU (max occupancy, same as R8) but half
// the preambles. Owner resolution by direct interval scatter into a
// 32-entry LDS window (thread tid owns token tid's [p-d, p) span) —
// no cum[] array, no binary search, 160 B LDS.
__global__ __launch_bounds__(BLK) void lenreg(const f32x4* __restrict__ xs,
                                              const int* __restrict__ ds,
                                              f32x4* __restrict__ out) {
    const int b       = blockIdx.x & 7;             // batch -> XCD pin
    const int rowbase = (blockIdx.x >> 3) * TROWS;  // first output frame
    const int tid     = threadIdx.x;                // 0..511 = token index

    __shared__ int wsum[BLK / 64];  // 8 per-wave scan totals
    __shared__ int owner[TROWS];    // owning token per row (-1 = empty)

    // ---- Phase A: inclusive scan of ds[b] (one token per thread) ----
    const int d = ds[b * NIN + tid];
    int p = d;
    const int lane = tid & 63;
    const int wid  = tid >> 6;
    #pragma unroll
    for (int off = 1; off < 64; off <<= 1) {
        int v = __shfl_up(p, off, 64);
        if (lane >= off) p += v;
    }
    if (lane == 63) wsum[wid] = p;
    if (tid < TROWS) owner[tid] = -1;   // init window while scan settles
    __syncthreads();
    int acc = 0;
    #pragma unroll
    for (int w = 0; w < BLK / 64; ++w)
        if (w < wid) acc += wsum[w];
    p += acc;                           // inclusive cumsum for token tid

    // ---- Phase B: scatter tid into the rows this token owns ----
    {
        int lo = p - d;                 // interval [lo, p)
        if (lo < rowbase) lo = rowbase;
        int hi = p;
        if (hi > rowbase + TROWS) hi = rowbase + TROWS;
        for (int t = lo; t < hi; ++t) owner[t - rowbase] = tid;
    }
    __syncthreads();

    // ---- Phase C: 6 preloaded load->store pairs, fully coalesced ----
    const f32x4* xsb  = xs + (size_t)b * NIN * J4;
    f32x4*       outb = out + ((size_t)b * TOUT + rowbase) * J4;
    constexpr int ITER = TROWS * J4 / BLK;          // 6
    int   o[ITER];
    f32x4 v[ITER];
    #pragma unroll
    for (int k = 0; k < ITER; ++k)
        o[k] = owner[(k * BLK + tid) / J4];
    #pragma unroll
    for (int k = 0; k < ITER; ++k) {
        const int g = k * BLK + tid;                // 0..3071
        const int j = g - (g / J4) * J4;            // float4 within row
        v[k] = (f32x4)(0.f);
        if (o[k] >= 0) v[k] = xsb[o[k] * J4 + j];
    }
    #pragma unroll
    for (int k = 0; k < ITER; ++k)
        outb[k * BLK + tid] = v[k];
}

extern "C" void kernel_launch(void* const* d_in, const int* in_sizes, int n_in,
                              void* d_out, int out_size, void* d_ws, size_t ws_size,
                              hipStream_t stream) {
    const float* xs = (const float*)d_in[0];   // (8, 512, 384) f32
    const int*   ds = (const int*)d_in[1];     // (8, 512) int
    float* out = (float*)d_out;                // (8, 4096, 384) f32

    // 1D grid: low 3 bits = batch (XCD slot), high bits = row tile
    lenreg<<<(TOUT / TROWS) * NB, BLK, 0, stream>>>((const f32x4*)xs, ds,
                                                    (f32x4*)out);
}

// Round 12
// 74.278 us; speedup vs baseline: 1.0480x; 1.0480x over previous
//
#include <hip/hip_runtime.h>

#define NB    8
#define NIN   512
#define TOUT  4096
#define ND    384
#define J4    (ND / 4)     // 96 float4 per row
#define TROWS 16           // output rows per block
#define BLK   256          // threads per block (4 waves)

typedef float f32x4 __attribute__((ext_vector_type(4)));

// Fused length-regulator, R11 = R8 shape (BLK=256, TROWS=16, 2048 blocks =
// exact 8-blocks/CU residency, best measured) with the 10-step LDS-dependent
// binary search replaced by direct interval scatter: after the pair-scan each
// thread holds cum for its two tokens IN REGISTERS and scatters the token
// index into the 16-entry owner window. Removes ~1200 cyc of serial LDS
// chain from the preamble; LDS total = 96 B.
__global__ __launch_bounds__(BLK) void lenreg(const f32x4* __restrict__ xs,
                                              const int* __restrict__ ds,
                                              f32x4* __restrict__ out) {
    const int b       = blockIdx.x & 7;             // batch -> XCD pin
    const int rowbase = (blockIdx.x >> 3) * TROWS;  // first output frame
    const int tid     = threadIdx.x;

    __shared__ int wsum[BLK / 64];  // 4 per-wave scan totals
    __shared__ int owner[TROWS];    // owning token per row (-1 = empty)

    // ---- Phase A: pair-scan of ds[b][0..511] (2 tokens per thread) ----
    const int* dsb = ds + b * NIN;
    const int a0 = dsb[2 * tid];
    const int a1 = dsb[2 * tid + 1];
    int p = a0 + a1;                // pair sum
    const int lane = tid & 63;
    const int wid  = tid >> 6;
    #pragma unroll
    for (int off = 1; off < 64; off <<= 1) {
        int v = __shfl_up(p, off, 64);
        if (lane >= off) p += v;
    }
    if (lane == 63) wsum[wid] = p;
    if (tid < TROWS) owner[tid] = -1;   // init window before scatter
    __syncthreads();
    int acc = 0;
    #pragma unroll
    for (int w = 0; w < BLK / 64; ++w)
        if (w < wid) acc += wsum[w];
    p += acc;                       // inclusive cum for token 2*tid+1

    // ---- Phase B: scatter this thread's two token intervals ----
    // token 2*tid   owns [p-a1-a0, p-a1), token 2*tid+1 owns [p-a1, p)
    {
        const int c1 = p, c0 = p - a1, left = c0 - a0;
        const int wlo = rowbase, whi = rowbase + TROWS;
        int l0 = left < wlo ? wlo : left;
        int h0 = c0  > whi ? whi : c0;
        for (int t = l0; t < h0; ++t) owner[t - rowbase] = 2 * tid;
        int l1 = c0 < wlo ? wlo : c0;
        int h1 = c1 > whi ? whi : c1;
        for (int t = l1; t < h1; ++t) owner[t - rowbase] = 2 * tid + 1;
    }
    __syncthreads();

    // ---- Phase C: 6 preloaded load->store pairs, fully coalesced ----
    const f32x4* xsb  = xs + (size_t)b * NIN * J4;
    f32x4*       outb = out + ((size_t)b * TOUT + rowbase) * J4;
    constexpr int ITER = TROWS * J4 / BLK;          // 6
    int   o[ITER];
    f32x4 v[ITER];
    #pragma unroll
    for (int k = 0; k < ITER; ++k)
        o[k] = owner[(k * BLK + tid) / J4];
    #pragma unroll
    for (int k = 0; k < ITER; ++k) {
        const int g = k * BLK + tid;                // 0..1535
        const int j = g - (g / J4) * J4;            // float4 within row
        v[k] = (f32x4)(0.f);
        if (o[k] >= 0) v[k] = xsb[o[k] * J4 + j];
    }
    #pragma unroll
    for (int k = 0; k < ITER; ++k)
        outb[k * BLK + tid] = v[k];
}

extern "C" void kernel_launch(void* const* d_in, const int* in_sizes, int n_in,
                              void* d_out, int out_size, void* d_ws, size_t ws_size,
                              hipStream_t stream) {
    const float* xs = (const float*)d_in[0];   // (8, 512, 384) f32
    const int*   ds = (const int*)d_in[1];     // (8, 512) int
    float* out = (float*)d_out;                // (8, 4096, 384) f32

    // 1D grid: low 3 bits = batch (XCD slot), high bits = row tile
    lenreg<<<(TOUT / TROWS) * NB, BLK, 0, stream>>>((const f32x4*)xs, ds,
                                                    (f32x4*)out);
}